// Round 7
// baseline (73.582 us; speedup 1.0000x reference)
//
#include <hip/hip_runtime.h>
#include <math.h>

#define H    64
#define N    256
#define D    128
#define L    16
#define SEG4   112                 // float4 per 448-col segment
#define F3IN (N * 448)             // 114688 floats per W1 row
#define CG4   1792                 // float4 per column group (16 segments)

typedef float v4f __attribute__((ext_vector_type(4)));

__device__ __forceinline__ float sigmoidf_(float x) {
    return 1.0f / (1.0f + expf(-x));
}
__device__ __forceinline__ float dot4(float4 a, float4 b) {
    return a.x * b.x + a.y * b.y + a.z * b.z + a.w * b.w;
}
__device__ __forceinline__ float dotv(v4f a, v4f b) {
    return a[0] * b[0] + a[1] * b[1] + a[2] * b[2] + a[3] * b[3];
}

// ---------------------------------------------------------------------------
// Kernel 1: encoder. emb gather + gi hoist + GRU(16 steps, 2 barriers each) +
// f1W transform + factored flat softmax (wave-shuffle reductions, 2 barriers).
// Z_ij = u_i + v_j + const; const cancels. Outputs g[64], eus[256], ev[256].
// ---------------------------------------------------------------------------
__global__ __launch_bounds__(256, 1) void k_enc(
    const int* __restrict__ token_ids, const float* __restrict__ emb_table,
    const float* __restrict__ Wih, const float* __restrict__ Whh,
    const float* __restrict__ bih, const float* __restrict__ bhh,
    const float* __restrict__ f1W, const float* __restrict__ obs,
    float* __restrict__ g_out, float* __restrict__ eus_out,
    float* __restrict__ ev_out)
{
    __shared__ float emb_s[L * H];
    __shared__ float gi_all[L * 192];
    __shared__ float h_s[H];
    __shared__ float gh_s[192];
    __shared__ float wa_s[D];
    __shared__ float wb_s[D];
    __shared__ float wred[4][4];    // [quantity][wave]

    const int k = threadIdx.x;
    const int wave = k >> 6, lane = k & 63;

    {
        int tok = token_ids[k >> 4];
        ((float4*)emb_s)[k] = ((const float4*)emb_table)[tok * 16 + (k & 15)];
    }
    if (k < H) h_s[k] = 0.0f;

    float4 wih4[16], whh4[16];
    float bi = 0.0f, bh = 0.0f;
    if (k < 192) {
        const float4* wi = (const float4*)(Wih + k * H);
        const float4* wh = (const float4*)(Whh + k * H);
#pragma unroll
        for (int c = 0; c < 16; ++c) { wih4[c] = wi[c]; whh4[c] = wh[c]; }
        bi = bih[k]; bh = bhh[k];
    }

    float f1wreg[64];
#pragma unroll
    for (int kk = 0; kk < 64; ++kk) f1wreg[kk] = f1W[kk * 256 + k];

    __syncthreads();

    if (k < 192) {
        float gi[L];
#pragma unroll
        for (int tt = 0; tt < L; ++tt) gi[tt] = bi;
#pragma unroll
        for (int c = 0; c < 16; ++c) {
            float4 w = wih4[c];
#pragma unroll
            for (int tt = 0; tt < L; ++tt)
                gi[tt] += dot4(w, ((const float4*)(emb_s + tt * 64))[c]);
        }
#pragma unroll
        for (int tt = 0; tt < L; ++tt) gi_all[tt * 192 + k] = gi[tt];
    }
    __syncthreads();

    for (int tt = 0; tt < L; ++tt) {
        if (k < 192) {
            const float4* hv = (const float4*)h_s;
            float a0 = 0, a1 = 0, a2 = 0, a3 = 0;
#pragma unroll
            for (int c = 0; c < 16; c += 4) {
                a0 += dot4(whh4[c],     hv[c]);
                a1 += dot4(whh4[c + 1], hv[c + 1]);
                a2 += dot4(whh4[c + 2], hv[c + 2]);
                a3 += dot4(whh4[c + 3], hv[c + 3]);
            }
            gh_s[k] = (a0 + a1) + (a2 + a3) + bh;
        }
        __syncthreads();
        if (k < H) {
            float r = sigmoidf_(gi_all[tt * 192 + k] + gh_s[k]);
            float z = sigmoidf_(gi_all[tt * 192 + 64 + k] + gh_s[64 + k]);
            float n = tanhf(gi_all[tt * 192 + 128 + k] + r * gh_s[128 + k]);
            h_s[k] = (1.0f - z) * n + z * h_s[k];
        }
        __syncthreads();
    }

    {
        float s = 0.0f;
#pragma unroll
        for (int kk = 0; kk < 64; ++kk) s += f1wreg[kk] * h_s[kk];
        if (k < D) wa_s[k] = s;
        else       wb_s[k - D] = s;
        if (k < H) g_out[k] = h_s[k];
    }
    __syncthreads();

    float4 orow[32];
    {
        const float4* rp = (const float4*)(obs + k * D);
#pragma unroll
        for (int c = 0; c < 32; ++c) orow[c] = rp[c];
    }
    float u = 0.0f, v = 0.0f;
#pragma unroll
    for (int c = 0; c < 32; ++c) {
        u += dot4(orow[c], ((const float4*)wa_s)[c]);
        v += dot4(orow[c], ((const float4*)wb_s)[c]);
    }

    // wave-shuffle max reduce for u, v
    float um = u, vm = v;
#pragma unroll
    for (int off = 32; off > 0; off >>= 1) {
        um = fmaxf(um, __shfl_xor(um, off, 64));
        vm = fmaxf(vm, __shfl_xor(vm, off, 64));
    }
    if (lane == 0) { wred[0][wave] = um; wred[1][wave] = vm; }
    __syncthreads();
    const float mu = fmaxf(fmaxf(wred[0][0], wred[0][1]), fmaxf(wred[0][2], wred[0][3]));
    const float mv = fmaxf(fmaxf(wred[1][0], wred[1][1]), fmaxf(wred[1][2], wred[1][3]));

    const float eui = expf(u - mu), evi = expf(v - mv);
    float us = eui, vs = evi;
#pragma unroll
    for (int off = 32; off > 0; off >>= 1) {
        us += __shfl_xor(us, off, 64);
        vs += __shfl_xor(vs, off, 64);
    }
    if (lane == 0) { wred[2][wave] = us; wred[3][wave] = vs; }
    __syncthreads();
    const float Su = (wred[2][0] + wred[2][1]) + (wred[2][2] + wred[2][3]);
    const float Sv = (wred[3][0] + wred[3][1]) + (wred[3][2] + wred[3][3]);

    eus_out[k] = eui * (1.0f / (Su * Sv));
    ev_out[k]  = evi;
}

// ---------------------------------------------------------------------------
// Kernel 2: W1 matvec with virtual x. Block (rg, cg): rows {2rg, 2rg+1} over
// column-group cg. Each WAVE owns a contiguous 7 KiB span per row (448 f4):
// clean per-wave sequential DRAM streams. x-slice in 7 regs/thread. Default
// cache behavior (no nontemporal) to maximize L3 residency of W1.
// ---------------------------------------------------------------------------
__global__ __launch_bounds__(256, 4) void k_mv(
    const float* __restrict__ W1, const float* __restrict__ obs,
    const float* __restrict__ g, const float* __restrict__ eus,
    const float* __restrict__ ev, float* __restrict__ partial)
{
    const int t  = threadIdx.x;
    const int cg = blockIdx.x & 15;
    const int rg = blockIdx.x >> 4;        // 0..255
    const int wave = t >> 6, lane = t & 63;

    // virtual-x slice: xr[j] = x[cg*1792 + wave*448 + j*64 + lane]
    v4f xr[7];
    {
        const float4* obs4 = (const float4*)obs;
        const float4* g4   = (const float4*)g;
        const float4* ev4  = (const float4*)ev;
#pragma unroll
        for (int j = 0; j < 7; ++j) {
            int idx = wave * 448 + j * 64 + lane;   // < 1792
            int s   = idx / SEG4;
            int c   = idx - s * SEG4;
            int seg = cg * 16 + s;
            float4 o;
            if (c < 32)       o = obs4[seg * 32 + c];
            else if (c < 48)  o = g4[c - 32];
            else {
                float4 e = ev4[c - 48];
                float m = eus[seg];
                o = make_float4(e.x * m, e.y * m, e.z * m, e.w * m);
            }
            xr[j] = (v4f){o.x, o.y, o.z, o.w};
        }
    }

    // two rows; each wave streams 7 x 1KB consecutive lines per row
    const v4f* w0 = (const v4f*)W1 + (size_t)(rg * 2) * (F3IN / 4)
                  + (size_t)cg * CG4 + wave * 448 + lane;
    const v4f* w1 = w0 + (F3IN / 4);

    float s0a = 0.0f, s0b = 0.0f, s1a = 0.0f, s1b = 0.0f;
#pragma unroll
    for (int j = 0; j < 7; ++j) {
        v4f wa = w0[j * 64];
        v4f wb = w1[j * 64];
        float da = dotv(wa, xr[j]);
        float db = dotv(wb, xr[j]);
        if (j & 1) { s0b += da; s1b += db; }
        else       { s0a += da; s1a += db; }
    }
    float sums[2] = { s0a + s0b, s1a + s1b };

    __shared__ float red[2][4];
#pragma unroll
    for (int rr = 0; rr < 2; ++rr) {
        float s = sums[rr];
#pragma unroll
        for (int off = 32; off > 0; off >>= 1) s += __shfl_down(s, off, 64);
        if (lane == 0) red[rr][wave] = s;
    }
    __syncthreads();
    if (t < 2)
        partial[(rg * 2 + t) * 16 + cg] =
            red[t][0] + red[t][1] + red[t][2] + red[t][3];
}

// ---------------------------------------------------------------------------
// Kernel 3: h1 = relu(sum of 16 partials + b1); out = W2 @ h1 + b2. One block.
// ---------------------------------------------------------------------------
__global__ __launch_bounds__(512) void k_finish(
    const float* __restrict__ partial, const float* __restrict__ b1,
    const float* __restrict__ W2, const float* __restrict__ b2,
    float* __restrict__ out)
{
    __shared__ float h1s[512];
    const int r = threadIdx.x;
    {
        const float4* p4 = (const float4*)(partial + r * 16);
        float4 A = p4[0], B = p4[1], C = p4[2], E = p4[3];
        float s = (A.x + A.y + A.z + A.w) + (B.x + B.y + B.z + B.w)
                + (C.x + C.y + C.z + C.w) + (E.x + E.y + E.z + E.w);
        h1s[r] = fmaxf(s + b1[r], 0.0f);
    }
    __syncthreads();

    const int wave = r >> 6, lane = r & 63;
    for (int row = wave; row < 40; row += 8) {
        float s = 0.0f;
#pragma unroll
        for (int c = 0; c < 8; ++c)
            s += W2[row * 512 + lane + c * 64] * h1s[lane + c * 64];
#pragma unroll
        for (int off = 32; off > 0; off >>= 1) s += __shfl_down(s, off, 64);
        if (lane == 0) out[row] = s + b2[row];
    }
}

// ---------------------------------------------------------------------------
extern "C" void kernel_launch(void* const* d_in, const int* in_sizes, int n_in,
                              void* d_out, int out_size, void* d_ws, size_t ws_size,
                              hipStream_t stream)
{
    const float* obs       = (const float*)d_in[0];
    const int*   token_ids = (const int*)  d_in[1];
    const float* emb_table = (const float*)d_in[2];
    const float* Wih       = (const float*)d_in[3];
    const float* Whh       = (const float*)d_in[4];
    const float* bih       = (const float*)d_in[5];
    const float* bhh       = (const float*)d_in[6];
    const float* f1W       = (const float*)d_in[7];
    // d_in[8] = f1_b : cancels in the flat softmax (Z_ij = u_i + v_j + const)
    const float* W1        = (const float*)d_in[9];
    const float* b1        = (const float*)d_in[10];
    const float* W2        = (const float*)d_in[11];
    const float* b2        = (const float*)d_in[12];

    float* ws      = (float*)d_ws;
    float* g       = ws;            // 64
    float* eus     = ws + 64;       // 256
    float* ev      = ws + 320;      // 256
    float* partial = ws + 640;      // 512*16 = 8192
    float* out     = (float*)d_out;

    k_enc<<<1, 256, 0, stream>>>(token_ids, emb_table, Wih, Whh, bih, bhh,
                                 f1W, obs, g, eus, ev);
    k_mv<<<4096, 256, 0, stream>>>(W1, obs, g, eus, ev, partial);
    k_finish<<<1, 512, 0, stream>>>(partial, b1, W2, b2, out);
}